// Round 15
// baseline (153.710 us; speedup 1.0000x reference)
//
#include <hip/hip_runtime.h>
#include <hip/hip_fp16.h>

#define NN 100000    // nodes
#define NE 1000000   // edges
#define FD 64        // feature dim
#define CHK 64       // nodes per block tile in k_l1
#define CAP 32       // padded csr row capacity (max expected deg ~27)
#define OVFCAP 4096  // overflow edge capacity (expected usage: 0)

typedef _Float16 f16x2 __attribute__((ext_vector_type(2)));

#if defined(__has_builtin)
#if __has_builtin(__builtin_amdgcn_fdot2)
#define HAVE_FDOT2 1
#endif
#endif

__device__ __forceinline__ float fdot2f(__half2 a, __half2 b, float c) {
#ifdef HAVE_FDOT2
    return __builtin_amdgcn_fdot2(__builtin_bit_cast(f16x2, a),
                                  __builtin_bit_cast(f16x2, b), c, false);
#else
    const float2 af = __half22float2(a), bf = __half22float2(b);
    return c + af.x * bf.x + af.y * bf.y;
#endif
}

// ws layout (4-byte units):
//   cnt  : [0, NN)            int   (degree counter; final value = deg)
//   ovfc : [NN]               int   (overflow counter; +3 pad)
//   ovf  : [NN+4, +2*OVFCAP)  int   (overflow (dst, src<<7) pairs)
//   csr  : [OFF_CSR, +32*NN)  int   (padded rows: src<<7 byte offsets)
//   pq   : next 4NN floats
//   wth  : next 2*2048 half2  (W1l^T, W1r^T packed f16 [j2][k])
//   xh   : next (NN+1)*64 halves (f16 x; row NN = zeros)
// total ~ 27.7 MB (<= 28.4 MB proven in R1)

#define OFF_CNT 0
#define OFF_OVFC (NN)
#define OFF_OVF (NN + 4)
#define OFF_CSR (NN + 4 + 2 * OVFCAP)
#define OFF_PQ  (OFF_CSR + CAP * NN)
#define OFF_WTH (OFF_PQ + 4 * NN)
#define OFF_XH  (OFF_WTH + 4096)

struct alignas(16) H8 { __half2 h[4]; };

#define NA4 (NE / 4)       // 250000: atomic+scatter threads (4 edges each)
#define NB4 (2 * NE / 4)   // 500000: edge_out conversion threads
#define NCC (NN * FD / 8)  // 800000: cast threads

// ---------------------------------------------------------------------------
// K1 (fused one-pass build; disjoint thread ranges, atomics first):
//   [0, NA4)      : r = atomicAdd(&cnt[dst]); csr[dst*32+r] = src<<7
//                   (r>=32 -> exact overflow list). The returning atomic IS
//                   the CSR slot allocator: no rank array, no scan, no
//                   separate build pass.
//   [.., +NB4)    : edge_index -> float output tail (int4/float4)
//   [.., +NCC)    : x -> f16 copy (8 elems/thread)
//   next 8        : zero pad row
//   next 2048     : pack W1l^T, W1r^T to f16 half2 [j2][k]
__global__ __launch_bounds__(256) void k_build(
    const int* __restrict__ ei, int* __restrict__ cnt, int* __restrict__ ovfc,
    int* __restrict__ ovf, int* __restrict__ csr, float* __restrict__ edge_out,
    const float* __restrict__ x, __half* __restrict__ xh,
    const float* __restrict__ W1l, const float* __restrict__ W1r,
    __half2* __restrict__ wt1lh, __half2* __restrict__ wt1rh) {
    const int tid = blockIdx.x * blockDim.x + threadIdx.x;
    if (tid < NA4) {
        const int4 s = *((const int4*)ei + tid);
        const int4 d = *((const int4*)(ei + NE) + tid);
        const int r0 = atomicAdd(&cnt[d.x], 1);
        const int r1 = atomicAdd(&cnt[d.y], 1);
        const int r2 = atomicAdd(&cnt[d.z], 1);
        const int r3 = atomicAdd(&cnt[d.w], 1);
        if (r0 < CAP) csr[(d.x << 5) + r0] = s.x << 7;
        else { int o = atomicAdd(ovfc, 1); if (o < OVFCAP) { ovf[2 * o] = d.x; ovf[2 * o + 1] = s.x << 7; } }
        if (r1 < CAP) csr[(d.y << 5) + r1] = s.y << 7;
        else { int o = atomicAdd(ovfc, 1); if (o < OVFCAP) { ovf[2 * o] = d.y; ovf[2 * o + 1] = s.y << 7; } }
        if (r2 < CAP) csr[(d.z << 5) + r2] = s.z << 7;
        else { int o = atomicAdd(ovfc, 1); if (o < OVFCAP) { ovf[2 * o] = d.z; ovf[2 * o + 1] = s.z << 7; } }
        if (r3 < CAP) csr[(d.w << 5) + r3] = s.w << 7;
        else { int o = atomicAdd(ovfc, 1); if (o < OVFCAP) { ovf[2 * o] = d.w; ovf[2 * o + 1] = s.w << 7; } }
    } else if (tid < NA4 + NB4) {
        const int i = tid - NA4;
        const int4 v = *((const int4*)ei + i);
        float4 f;
        f.x = (float)v.x; f.y = (float)v.y; f.z = (float)v.z; f.w = (float)v.w;
        *((float4*)edge_out + i) = f;
    } else if (tid < NA4 + NB4 + NCC) {
        const int i = tid - NA4 - NB4;
        const float4 a = *((const float4*)x + (size_t)i * 2);
        const float4 b = *((const float4*)x + (size_t)i * 2 + 1);
        H8 o;
        o.h[0] = __floats2half2_rn(a.x, a.y);
        o.h[1] = __floats2half2_rn(a.z, a.w);
        o.h[2] = __floats2half2_rn(b.x, b.y);
        o.h[3] = __floats2half2_rn(b.z, b.w);
        *((H8*)xh + i) = o;
    } else if (tid < NA4 + NB4 + NCC + 8) {
        H8 z;
        z.h[0] = z.h[1] = z.h[2] = z.h[3] = __float2half2_rn(0.f);
        *((H8*)(xh + (size_t)NN * FD) + (tid - NA4 - NB4 - NCC)) = z;
    } else if (tid < NA4 + NB4 + NCC + 8 + 2048) {
        const int i = tid - (NA4 + NB4 + NCC + 8);   // j2*64 + k
        const int j2 = i >> 6, k = i & 63;
        wt1lh[i] = __floats2half2_rn(W1l[k * FD + 2 * j2], W1l[k * FD + 2 * j2 + 1]);
        wt1rh[i] = __floats2half2_rn(W1r[k * FD + 2 * j2], W1r[k * FD + 2 * j2 + 1]);
    }
}

// ---------------------------------------------------------------------------
// K2: fused layer-1, 64-node tile per block (8 waves, 512 threads).
//  phase A (R13 config, 8-deep): 8 groups of 8 lanes; group owns one node;
//    lane loads 16B = 8 f16 of the 128B neighbor row from the PADDED csr
//    (row base = n*32, no rowstart). Invalid slots -> zero row (maskless
//    garbage-proof). deg>CAP remainder drained from the overflow list.
//  phase B: packed half2 j-pairs + v_dot2_f32_f16 (2 MAC/instr, f32 accum).
__global__ __launch_bounds__(512, 8) void k_l1(
    const int* __restrict__ csr, const int* __restrict__ cnt,
    const int* __restrict__ ovfc, const int* __restrict__ ovf,
    const __half* __restrict__ xh,
    const __half2* __restrict__ wt1lh, const float* __restrict__ b1,
    const __half2* __restrict__ wt1rh,
    const float* __restrict__ W2l, const float* __restrict__ b2,
    const float* __restrict__ W2r,
    float* __restrict__ pq) {
    __shared__ __half2 sH[FD / 2][CHK + 1];   // 8.3 KB
    __shared__ __half2 xH[FD / 2][CHK + 1];   // 8.3 KB
    __shared__ float pacc[4 * CHK];           // 1 KB
    const int lane = threadIdx.x & 63;
    const int wid = threadIdx.x >> 6;   // 0..7
    const int g = lane >> 3;            // group 0..7
    const int sl = lane & 7;            // lane within group
    const int gb = g << 3;              // group base lane
    const int base = blockIdx.x * CHK;
    const char* xb = (const char*)xh;
    const unsigned slb = (unsigned)(sl << 4);   // 16B per lane
    const int ZOFF = NN << 7;                   // zero-row byte offset

    if (threadIdx.x < 4 * CHK) pacc[threadIdx.x] = 0.f;

    // ---- phase A: one node per group (8 nodes per wave) ----
    const int nl = wid * 8 + g;         // 0..63
    const int n = base + nl;
    const bool ok = n < NN;
    const int nn = ok ? n : NN - 1;
    const int d = cnt[nn];              // group-uniform (true degree)
    const int dmc = min(d, CAP);        // valid padded slots
    const int rs = nn << 5;             // padded row base

    int dmax = dmc;
    dmax = max(dmax, __shfl_xor(dmax, 8));
    dmax = max(dmax, __shfl_xor(dmax, 16));
    dmax = max(dmax, __shfl_xor(dmax, 32));
    const int nch = __builtin_amdgcn_readfirstlane((dmax + 7) >> 3);

    H8 acc;
    acc.h[0] = acc.h[1] = acc.h[2] = acc.h[3] = __float2half2_rn(0.f);

    for (int c = 0; c < nch; ++c) {
        const int jb = c << 3;
        const int raw = csr[rs + jb + sl];             // padded slot (<= 31)
        const int offs = (jb + sl < dmc) ? raw : ZOFF; // invalid -> zero row
        H8 buf[8];
#pragma unroll
        for (int t = 0; t < 8; ++t) {
            const unsigned ob = (unsigned)__shfl(offs, gb + t);
            buf[t] = *(const H8*)(xb + (size_t)(ob + slb));
        }
        __builtin_amdgcn_sched_barrier(0);  // keep 8 row-loads in flight
#pragma unroll
        for (int t = 0; t < 8; ++t) {
            acc.h[0] = __hadd2(acc.h[0], buf[t].h[0]);
            acc.h[1] = __hadd2(acc.h[1], buf[t].h[1]);
            acc.h[2] = __hadd2(acc.h[2], buf[t].h[2]);
            acc.h[3] = __hadd2(acc.h[3], buf[t].h[3]);
        }
    }

    // ---- overflow drain (expected never taken; exactness guarantee) ----
    if (__builtin_expect(d > CAP, 0)) {
        const int oc = min(*ovfc, OVFCAP);
        for (int i = 0; i < oc; ++i) {
            if (ovf[2 * i] == nn) {
                const unsigned ob = (unsigned)ovf[2 * i + 1];
                const H8 b = *(const H8*)(xb + (size_t)(ob + slb));
                acc.h[0] = __hadd2(acc.h[0], b.h[0]);
                acc.h[1] = __hadd2(acc.h[1], b.h[1]);
                acc.h[2] = __hadd2(acc.h[2], b.h[2]);
                acc.h[3] = __hadd2(acc.h[3], b.h[3]);
            }
        }
    }

    if (ok) {
        const __half2 hinv = __float2half2_rn(1.0f / (float)max(d, 1));
        const H8 xv = *(const H8*)(xb + (size_t)(((unsigned)nn << 7) + slb));
#pragma unroll
        for (int t = 0; t < 4; ++t) {
            sH[sl * 4 + t][nl] = __hmul2(acc.h[t], hinv);
            xH[sl * 4 + t][nl] = xv.h[t];
        }
    }
    __syncthreads();

    // ---- phase B: lane = node, k-slice [kbase, kbase+8), packed j-pairs ----
    const int kbase = __builtin_amdgcn_readfirstlane(wid * 8);
    float h[8];
#pragma unroll
    for (int t = 0; t < 8; ++t) h[t] = b1[kbase + t];
#pragma unroll 4
    for (int j2 = 0; j2 < FD / 2; ++j2) {
        const __half2 sj = sH[j2][lane];
        const __half2 xj = xH[j2][lane];
        const __half2* wl = wt1lh + j2 * FD + kbase;   // wave-uniform
        const __half2* wr = wt1rh + j2 * FD + kbase;
#pragma unroll
        for (int t = 0; t < 8; ++t) {
            h[t] = fdot2f(sj, wl[t], h[t]);
            h[t] = fdot2f(xj, wr[t], h[t]);
        }
    }

    float p0 = 0.f, p1 = 0.f, q0 = 0.f, q1 = 0.f;
#pragma unroll
    for (int t = 0; t < 8; ++t) {
        const float r = fmaxf(h[t], 0.f);
        p0 += r * W2l[kbase + t];
        p1 += r * W2l[FD + kbase + t];
        q0 += r * W2r[kbase + t];
        q1 += r * W2r[FD + kbase + t];
    }
    atomicAdd(&pacc[0 * CHK + lane], p0);
    atomicAdd(&pacc[1 * CHK + lane], p1);
    atomicAdd(&pacc[2 * CHK + lane], q0);
    atomicAdd(&pacc[3 * CHK + lane], q1);
    __syncthreads();

    // ---- write pq: thread t -> (node t>>2, comp t&3), coalesced ----
    {
        const int t = threadIdx.x;
        if (t < 4 * CHK) {
            const int nw = base + (t >> 2);
            if (nw < NN) {
                const int c = t & 3;
                float v = pacc[c * CHK + (t >> 2)];
                if (c == 2) v += b2[0];
                if (c == 3) v += b2[1];
                pq[(size_t)nw * 4 + c] = v;
            }
        }
    }
}

// ---------------------------------------------------------------------------
// K3: layer-2 mean aggregation of p + final add. 16 lanes per node,
//     4 nodes per wave. Padded csr rows; overflow drained the same way.
//     csr holds src<<7; pq byte offset = src*16 = v>>3.
__global__ void k_l2(const int* __restrict__ csr, const int* __restrict__ cnt,
                     const int* __restrict__ ovfc, const int* __restrict__ ovf,
                     const float* __restrict__ pq, float* __restrict__ out) {
    const int gw = (blockIdx.x * blockDim.x + threadIdx.x) >> 6;
    const int lane = threadIdx.x & 63;
    const int sub = lane >> 4;   // node within wave
    const int sl = lane & 15;    // lane within 16-group
    const int n = gw * 4 + sub;
    if (n >= NN) return;
    const int d = cnt[n];
    const int dm = min(d, CAP);
    const char* pb = (const char*)pq;
    float a0 = 0.f, a1 = 0.f;
    for (int i = sl; i < dm; i += 16) {
        const unsigned v = (unsigned)csr[(n << 5) + i];
        const float2 p = *(const float2*)(pb + (size_t)(v >> 3));
        a0 += p.x;
        a1 += p.y;
    }
    if (__builtin_expect(d > CAP, 0)) {
        const int oc = min(*ovfc, OVFCAP);
        for (int i = sl; i < oc; i += 16) {
            if (ovf[2 * i] == n) {
                const unsigned v = (unsigned)ovf[2 * i + 1];
                const float2 p = *(const float2*)(pb + (size_t)(v >> 3));
                a0 += p.x;
                a1 += p.y;
            }
        }
    }
#pragma unroll
    for (int off = 8; off; off >>= 1) {
        a0 += __shfl_xor(a0, off);
        a1 += __shfl_xor(a1, off);
    }
    if (sl == 0) {
        const float inv = 1.0f / (float)max(d, 1);
        const float2 q = *(const float2*)(pq + 4 * (size_t)n + 2);
        *(float2*)(out + 2 * (size_t)n) = make_float2(a0 * inv + q.x, a1 * inv + q.y);
    }
}

// ---------------------------------------------------------------------------
extern "C" void kernel_launch(void* const* d_in, const int* in_sizes, int n_in,
                              void* d_out, int out_size, void* d_ws, size_t ws_size,
                              hipStream_t stream) {
    const float* x   = (const float*)d_in[0];
    const int*   ei  = (const int*)d_in[1];
    const float* W1l = (const float*)d_in[2];
    const float* b1  = (const float*)d_in[3];
    const float* W1r = (const float*)d_in[4];
    const float* W2l = (const float*)d_in[5];
    const float* b2  = (const float*)d_in[6];
    const float* W2r = (const float*)d_in[7];

    float* out      = (float*)d_out;   // N*2 floats
    float* edge_out = out + 2 * NN;    // 2*E floats (edge_index as float)

    int*    wsi   = (int*)d_ws;
    int*    cnt   = wsi + OFF_CNT;
    int*    ovfc  = wsi + OFF_OVFC;
    int*    ovf   = wsi + OFF_OVF;
    int*    csr   = wsi + OFF_CSR;
    float*  pq    = (float*)d_ws + OFF_PQ;
    __half2* wt1lh = (__half2*)((float*)d_ws + OFF_WTH);
    __half2* wt1rh = wt1lh + 2048;
    __half*  xh    = (__half*)((float*)d_ws + OFF_XH);

    // zero cnt + ovfc (contiguous)
    hipMemsetAsync(cnt, 0, (size_t)(NN + 1) * sizeof(int), stream);

    const int nbld = NA4 + NB4 + NCC + 8 + 2048;
    k_build<<<(nbld + 255) / 256, 256, 0, stream>>>(
        ei, cnt, ovfc, ovf, csr, edge_out, x, xh, W1l, W1r, wt1lh, wt1rh);
    k_l1<<<(NN + CHK - 1) / CHK, 512, 0, stream>>>(
        csr, cnt, ovfc, ovf, xh, wt1lh, b1, wt1rh, W2l, b2, W2r, pq);
    k_l2<<<((NN + 3) / 4 * 64 + 255) / 256, 256, 0, stream>>>(
        csr, cnt, ovfc, ovf, pq, out);
}

// Round 16
// 133.534 us; speedup vs baseline: 1.1511x; 1.1511x over previous
//
#include <hip/hip_runtime.h>
#include <hip/hip_fp16.h>

#define NN 100000    // nodes
#define NE 1000000   // edges
#define FD 64        // feature dim
#define CHK 64       // nodes per block tile in k_l1
#define NBUC 98      // buckets of 1024 nodes (dst >> 10)
#define NHB 256      // histogram / binning blocks
#define PB 3907      // edges per binning block (ceil)

typedef _Float16 f16x2 __attribute__((ext_vector_type(2)));

#if defined(__has_builtin)
#if __has_builtin(__builtin_amdgcn_fdot2)
#define HAVE_FDOT2 1
#endif
#endif

__device__ __forceinline__ float fdot2f(__half2 a, __half2 b, float c) {
#ifdef HAVE_FDOT2
    return __builtin_amdgcn_fdot2(__builtin_bit_cast(f16x2, a),
                                  __builtin_bit_cast(f16x2, b), c, false);
#else
    const float2 af = __half22float2(a), bf = __half22float2(b);
    return c + af.x * bf.x + af.y * bf.y;
#endif
}

// ws layout (4-byte units), total ~25.4 MB (<= 28.4 proven):
#define OFF_HIST 0                         // 256*98 per-block histograms
#define OFF_OFFG (NHB * NBUC)              // 256*98 (block,bucket) offsets
#define OFF_BS   (2 * NHB * NBUC)          // 99 bucket starts (+pad to 100)
#define OFF_BSRC (2 * NHB * NBUC + 100)    // NE   binned src<<7
#define OFF_BDST (OFF_BSRC + NE)           // NE/2 binned local dst (ushort)
#define OFF_ROW  (OFF_BDST + NE / 2)       // NN   rowstart
#define OFF_DEG  (OFF_ROW + NN)            // NN   degree
#define OFF_CSR  (OFF_DEG + NN)            // NE   src<<7, dst-grouped
#define OFF_PQ   (OFF_CSR + NE)            // 4NN
#define OFF_WTH  (OFF_PQ + 4 * NN)         // 2*2048 half2
#define OFF_XH   (OFF_WTH + 4096)          // (NN+1)*64 halves

struct alignas(16) H8 { __half2 h[4]; };

#define NB4 (2 * NE / 4)   // 500000 edge_out threads
#define NCC (NN * FD / 8)  // 800000 cast threads
#define NSTR (NB4 + NCC + 8 + 2048)

// ---------------------------------------------------------------------------
// K_A: blocks [0,NHB): per-block LDS histogram of dst buckets -> hist[b][k].
//      blocks [NHB,..): streaming — edge_out conversion, x->f16 cast,
//      zero row, f16 weight pack. NO global atomics anywhere.
__global__ __launch_bounds__(256) void k_A(
    const int* __restrict__ ei, int* __restrict__ hist,
    float* __restrict__ edge_out,
    const float* __restrict__ x, __half* __restrict__ xh,
    const float* __restrict__ W1l, const float* __restrict__ W1r,
    __half2* __restrict__ wt1lh, __half2* __restrict__ wt1rh) {
    if (blockIdx.x < NHB) {
        __shared__ int h[NBUC];
        const int t = threadIdx.x;
        if (t < NBUC) h[t] = 0;
        __syncthreads();
        const int e0 = blockIdx.x * PB;
        const int e1 = min(e0 + PB, NE);
        for (int e = e0 + t; e < e1; e += 256)
            atomicAdd(&h[ei[NE + e] >> 10], 1);
        __syncthreads();
        if (t < NBUC) hist[blockIdx.x * NBUC + t] = h[t];
        return;
    }
    const int tid = (blockIdx.x - NHB) * 256 + threadIdx.x;
    if (tid < NB4) {
        const int4 v = *((const int4*)ei + tid);
        float4 f;
        f.x = (float)v.x; f.y = (float)v.y; f.z = (float)v.z; f.w = (float)v.w;
        *((float4*)edge_out + tid) = f;
    } else if (tid < NB4 + NCC) {
        const int i = tid - NB4;
        const float4 a = *((const float4*)x + (size_t)i * 2);
        const float4 b = *((const float4*)x + (size_t)i * 2 + 1);
        H8 o;
        o.h[0] = __floats2half2_rn(a.x, a.y);
        o.h[1] = __floats2half2_rn(a.z, a.w);
        o.h[2] = __floats2half2_rn(b.x, b.y);
        o.h[3] = __floats2half2_rn(b.z, b.w);
        *((H8*)xh + i) = o;
    } else if (tid < NB4 + NCC + 8) {
        H8 z;
        z.h[0] = z.h[1] = z.h[2] = z.h[3] = __float2half2_rn(0.f);
        *((H8*)(xh + (size_t)NN * FD) + (tid - NB4 - NCC)) = z;
    } else if (tid < NSTR) {
        const int i = tid - (NB4 + NCC + 8);   // j2*64 + k
        const int j2 = i >> 6, k = i & 63;
        wt1lh[i] = __floats2half2_rn(W1l[k * FD + 2 * j2], W1l[k * FD + 2 * j2 + 1]);
        wt1rh[i] = __floats2half2_rn(W1r[k * FD + 2 * j2], W1r[k * FD + 2 * j2 + 1]);
    }
}

// ---------------------------------------------------------------------------
// K_B (1 block): off[b][k] = bucketStart[k] + sum_{b'<b} hist[b'][k].
__global__ __launch_bounds__(256) void k_B(const int* __restrict__ hist,
                                           int* __restrict__ offg,
                                           int* __restrict__ bucketStart) {
    __shared__ int total[NBUC];
    __shared__ int bs[NBUC + 1];
    const int t = threadIdx.x;
    if (t < NBUC) {
        int run = 0;
        for (int b = 0; b < NHB; ++b) {
            const int v = hist[b * NBUC + t];
            offg[b * NBUC + t] = run;
            run += v;
        }
        total[t] = run;
    }
    __syncthreads();
    if (t == 0) {
        int acc = 0;
        for (int k = 0; k < NBUC; ++k) { bs[k] = acc; acc += total[k]; }
        bs[NBUC] = acc;
    }
    __syncthreads();
    if (t < NBUC + 1) bucketStart[t] = bs[t];
    for (int i = t; i < NHB * NBUC; i += 256) offg[i] += bs[i % NBUC];
}

// ---------------------------------------------------------------------------
// K_C: 256 blocks re-read their edge chunk; LDS cursors (init from offg)
//      dole out slots; write bsrc (src<<7) + bdstl (dst&1023) bucket-binned.
__global__ __launch_bounds__(256) void k_C(const int* __restrict__ ei,
                                           const int* __restrict__ offg,
                                           int* __restrict__ bsrc,
                                           unsigned short* __restrict__ bdstl) {
    __shared__ int cur[NBUC];
    const int t = threadIdx.x;
    const int b = blockIdx.x;
    if (t < NBUC) cur[t] = offg[b * NBUC + t];
    __syncthreads();
    const int e0 = b * PB;
    const int e1 = min(e0 + PB, NE);
    for (int e = e0 + t; e < e1; e += 256) {
        const int d = ei[NE + e];
        const int s = ei[e];
        const int pos = atomicAdd(&cur[d >> 10], 1);
        bsrc[pos] = s << 7;
        bdstl[pos] = (unsigned short)(d & 1023);
    }
}

// ---------------------------------------------------------------------------
// K_D: one block per bucket (1024 threads): LDS degree count -> LDS scan ->
//      rowstart/deg (global, coalesced) -> LDS-atomic rank -> csr scatter
//      (bucket region ~41 KB, L2-local). No global atomics.
__global__ __launch_bounds__(1024) void k_D(const int* __restrict__ bsrc,
                                            const unsigned short* __restrict__ bdstl,
                                            const int* __restrict__ bucketStart,
                                            int* __restrict__ rowstart,
                                            int* __restrict__ deg,
                                            int* __restrict__ csr) {
    __shared__ int dcnt[1024];
    __shared__ int sc[1024];
    __shared__ int cur[1024];
    const int t = threadIdx.x;
    const int k = blockIdx.x;
    const int nbase = k << 10;
    const int eb0 = bucketStart[k];
    const int eb1 = bucketStart[k + 1];
    dcnt[t] = 0;
    __syncthreads();
    for (int e = eb0 + t; e < eb1; e += 1024)
        atomicAdd(&dcnt[bdstl[e]], 1);
    __syncthreads();
    const int v = dcnt[t];
    sc[t] = v;
    __syncthreads();
    for (int off = 1; off < 1024; off <<= 1) {
        const int add = (t >= off) ? sc[t - off] : 0;
        __syncthreads();
        sc[t] += add;
        __syncthreads();
    }
    const int rsl = eb0 + sc[t] - v;   // global rowstart for node nbase+t
    cur[t] = rsl;
    if (nbase + t < NN) {
        rowstart[nbase + t] = rsl;
        deg[nbase + t] = v;
    }
    __syncthreads();
    for (int e = eb0 + t; e < eb1; e += 1024) {
        const int dl = bdstl[e];
        const int pos = atomicAdd(&cur[dl], 1);
        csr[pos] = bsrc[e];   // already src<<7
    }
}

// ---------------------------------------------------------------------------
// k_l1: byte-identical structure to R13's proven 50.5us version.
__global__ __launch_bounds__(512, 8) void k_l1(
    const int* __restrict__ csr, const int* __restrict__ rowstart,
    const int* __restrict__ deg, const __half* __restrict__ xh,
    const __half2* __restrict__ wt1lh, const float* __restrict__ b1,
    const __half2* __restrict__ wt1rh,
    const float* __restrict__ W2l, const float* __restrict__ b2,
    const float* __restrict__ W2r,
    float* __restrict__ pq) {
    __shared__ __half2 sH[FD / 2][CHK + 1];
    __shared__ __half2 xH[FD / 2][CHK + 1];
    __shared__ float pacc[4 * CHK];
    const int lane = threadIdx.x & 63;
    const int wid = threadIdx.x >> 6;
    const int g = lane >> 3;
    const int sl = lane & 7;
    const int gb = g << 3;
    const int base = blockIdx.x * CHK;
    const char* xb = (const char*)xh;
    const unsigned slb = (unsigned)(sl << 4);
    const int ZOFF = NN << 7;

    if (threadIdx.x < 4 * CHK) pacc[threadIdx.x] = 0.f;

    const int nl = wid * 8 + g;
    const int n = base + nl;
    const bool ok = n < NN;
    const int nn = ok ? n : NN - 1;
    const int d = deg[nn];
    const int rs = rowstart[nn];

    int dmax = d;
    dmax = max(dmax, __shfl_xor(dmax, 8));
    dmax = max(dmax, __shfl_xor(dmax, 16));
    dmax = max(dmax, __shfl_xor(dmax, 32));
    const int nch = __builtin_amdgcn_readfirstlane((dmax + 7) >> 3);

    H8 acc;
    acc.h[0] = acc.h[1] = acc.h[2] = acc.h[3] = __float2half2_rn(0.f);

    for (int c = 0; c < nch; ++c) {
        const int jb = c << 3;
        const int ia = min(rs + jb + sl, NE - 1);
        const int raw = csr[ia];
        const int offs = (jb + sl < d) ? raw : ZOFF;
        H8 buf[8];
#pragma unroll
        for (int t = 0; t < 8; ++t) {
            const unsigned ob = (unsigned)__shfl(offs, gb + t);
            buf[t] = *(const H8*)(xb + (size_t)(ob + slb));
        }
        __builtin_amdgcn_sched_barrier(0);
#pragma unroll
        for (int t = 0; t < 8; ++t) {
            acc.h[0] = __hadd2(acc.h[0], buf[t].h[0]);
            acc.h[1] = __hadd2(acc.h[1], buf[t].h[1]);
            acc.h[2] = __hadd2(acc.h[2], buf[t].h[2]);
            acc.h[3] = __hadd2(acc.h[3], buf[t].h[3]);
        }
    }

    if (ok) {
        const __half2 hinv = __float2half2_rn(1.0f / (float)max(d, 1));
        const H8 xv = *(const H8*)(xb + (size_t)(((unsigned)nn << 7) + slb));
#pragma unroll
        for (int t = 0; t < 4; ++t) {
            sH[sl * 4 + t][nl] = __hmul2(acc.h[t], hinv);
            xH[sl * 4 + t][nl] = xv.h[t];
        }
    }
    __syncthreads();

    const int kbase = __builtin_amdgcn_readfirstlane(wid * 8);
    float h[8];
#pragma unroll
    for (int t = 0; t < 8; ++t) h[t] = b1[kbase + t];
#pragma unroll 4
    for (int j2 = 0; j2 < FD / 2; ++j2) {
        const __half2 sj = sH[j2][lane];
        const __half2 xj = xH[j2][lane];
        const __half2* wl = wt1lh + j2 * FD + kbase;
        const __half2* wr = wt1rh + j2 * FD + kbase;
#pragma unroll
        for (int t = 0; t < 8; ++t) {
            h[t] = fdot2f(sj, wl[t], h[t]);
            h[t] = fdot2f(xj, wr[t], h[t]);
        }
    }

    float p0 = 0.f, p1 = 0.f, q0 = 0.f, q1 = 0.f;
#pragma unroll
    for (int t = 0; t < 8; ++t) {
        const float r = fmaxf(h[t], 0.f);
        p0 += r * W2l[kbase + t];
        p1 += r * W2l[FD + kbase + t];
        q0 += r * W2r[kbase + t];
        q1 += r * W2r[FD + kbase + t];
    }
    atomicAdd(&pacc[0 * CHK + lane], p0);
    atomicAdd(&pacc[1 * CHK + lane], p1);
    atomicAdd(&pacc[2 * CHK + lane], q0);
    atomicAdd(&pacc[3 * CHK + lane], q1);
    __syncthreads();

    {
        const int t = threadIdx.x;
        if (t < 4 * CHK) {
            const int nw = base + (t >> 2);
            if (nw < NN) {
                const int c = t & 3;
                float vv = pacc[c * CHK + (t >> 2)];
                if (c == 2) vv += b2[0];
                if (c == 3) vv += b2[1];
                pq[(size_t)nw * 4 + c] = vv;
            }
        }
    }
}

// ---------------------------------------------------------------------------
// k_l2: layer-2 mean aggregation of p + final add (R13 version).
__global__ void k_l2(const int* __restrict__ csr, const int* __restrict__ rowstart,
                     const int* __restrict__ deg, const float* __restrict__ pq,
                     float* __restrict__ out) {
    const int gw = (blockIdx.x * blockDim.x + threadIdx.x) >> 6;
    const int lane = threadIdx.x & 63;
    const int sub = lane >> 4;
    const int sl = lane & 15;
    const int n = gw * 4 + sub;
    if (n >= NN) return;
    const int rs = rowstart[n];
    const int d = deg[n];
    const char* pb = (const char*)pq;
    float a0 = 0.f, a1 = 0.f;
    for (int i = sl; i < d; i += 16) {
        const unsigned v = (unsigned)csr[rs + i];
        const float2 p = *(const float2*)(pb + (size_t)(v >> 3));
        a0 += p.x;
        a1 += p.y;
    }
#pragma unroll
    for (int off = 8; off; off >>= 1) {
        a0 += __shfl_xor(a0, off);
        a1 += __shfl_xor(a1, off);
    }
    if (sl == 0) {
        const float inv = 1.0f / (float)max(d, 1);
        const float2 q = *(const float2*)(pq + 4 * (size_t)n + 2);
        *(float2*)(out + 2 * (size_t)n) = make_float2(a0 * inv + q.x, a1 * inv + q.y);
    }
}

// ---------------------------------------------------------------------------
extern "C" void kernel_launch(void* const* d_in, const int* in_sizes, int n_in,
                              void* d_out, int out_size, void* d_ws, size_t ws_size,
                              hipStream_t stream) {
    const float* x   = (const float*)d_in[0];
    const int*   ei  = (const int*)d_in[1];
    const float* W1l = (const float*)d_in[2];
    const float* b1  = (const float*)d_in[3];
    const float* W1r = (const float*)d_in[4];
    const float* W2l = (const float*)d_in[5];
    const float* b2  = (const float*)d_in[6];
    const float* W2r = (const float*)d_in[7];

    float* out      = (float*)d_out;   // N*2 floats
    float* edge_out = out + 2 * NN;    // 2*E floats

    int*    wsi      = (int*)d_ws;
    int*    hist     = wsi + OFF_HIST;
    int*    offg     = wsi + OFF_OFFG;
    int*    bstart   = wsi + OFF_BS;
    int*    bsrc     = wsi + OFF_BSRC;
    unsigned short* bdstl = (unsigned short*)(wsi + OFF_BDST);
    int*    rowstart = wsi + OFF_ROW;
    int*    deg      = wsi + OFF_DEG;
    int*    csr      = wsi + OFF_CSR;
    float*  pq       = (float*)d_ws + OFF_PQ;
    __half2* wt1lh   = (__half2*)((float*)d_ws + OFF_WTH);
    __half2* wt1rh   = wt1lh + 2048;
    __half*  xh      = (__half*)((float*)d_ws + OFF_XH);

    const int nstrb = (NSTR + 255) / 256;
    k_A<<<NHB + nstrb, 256, 0, stream>>>(ei, hist, edge_out, x, xh,
                                         W1l, W1r, wt1lh, wt1rh);
    k_B<<<1, 256, 0, stream>>>(hist, offg, bstart);
    k_C<<<NHB, 256, 0, stream>>>(ei, offg, bsrc, bdstl);
    k_D<<<NBUC, 1024, 0, stream>>>(bsrc, bdstl, bstart, rowstart, deg, csr);
    k_l1<<<(NN + CHK - 1) / CHK, 512, 0, stream>>>(csr, rowstart, deg, xh,
                                                   wt1lh, b1, wt1rh,
                                                   W2l, b2, W2r, pq);
    k_l2<<<((NN + 3) / 4 * 64 + 255) / 256, 256, 0, stream>>>(
        csr, rowstart, deg, pq, out);
}

// Round 17
// 108.557 us; speedup vs baseline: 1.4159x; 1.2301x over previous
//
#include <hip/hip_runtime.h>
#include <hip/hip_fp16.h>

#define NN 100000    // nodes
#define NE 1000000   // edges
#define FD 64        // feature dim
#define CHK 64       // nodes per block tile in k_l1
#define NBUC 98      // buckets of 1024 nodes (dst >> 10)
#define NHB 256      // binning blocks
#define PB 3907      // edges per binning block (ceil)
#define BCAP 12288   // bucket capacity (max fill ~10.5k, 20-sigma margin)

typedef _Float16 f16x2 __attribute__((ext_vector_type(2)));

#if defined(__has_builtin)
#if __has_builtin(__builtin_amdgcn_fdot2)
#define HAVE_FDOT2 1
#endif
#endif

__device__ __forceinline__ float fdot2f(__half2 a, __half2 b, float c) {
#ifdef HAVE_FDOT2
    return __builtin_amdgcn_fdot2(__builtin_bit_cast(f16x2, a),
                                  __builtin_bit_cast(f16x2, b), c, false);
#else
    const float2 af = __half22float2(a), bf = __half22float2(b);
    return c + af.x * bf.x + af.y * bf.y;
#endif
}

// ws layout (4-byte units), total ~27.2 MB (<= 28.4 proven):
#define OFF_CNT  0                          // 98 bucket cursors (+pad to 128)
#define OFF_BSRC 128                        // NBUC*BCAP binned src<<7
#define OFF_BDST (OFF_BSRC + NBUC * BCAP)   // NBUC*BCAP/2 local dst (ushort)
#define OFF_ROW  (OFF_BDST + NBUC * BCAP / 2)  // NN rowstart
#define OFF_DEG  (OFF_ROW + NN)             // NN degree
#define OFF_CSR  (OFF_DEG + NN)             // NBUC*BCAP src<<7, dst-grouped
#define OFF_PQ   (OFF_CSR + NBUC * BCAP)    // 4NN
#define OFF_WTH  (OFF_PQ + 4 * NN)          // 2*2048 half2
#define OFF_XH   (OFF_WTH + 4096)           // (NN+1)*64 halves

struct alignas(16) H8 { __half2 h[4]; };

#define NCC (NN * FD / 8)   // 800000 cast threads
#define NSTR (NCC + 8 + 2048)
#define NB4 (2 * NE / 4)    // 500000 edge_out int4 threads
#define NTILE ((NN + CHK - 1) / CHK)        // 1563 k_l1 tile blocks
#define NEOB ((NB4 + 511) / 512)            // 977 edge_out blocks in k_l1

// ---------------------------------------------------------------------------
// K1 k_bin: blocks [0,NHB): two-phase bin of edges by dst bucket.
//   pass1: LDS count per bucket; ONE global atomicAdd per (block,bucket)
//   reserves a contiguous region (25k global atomics total).
//   pass2: re-read chunk (L1/L2-hot), LDS-cursor scatter -> bsrc/bdstl.
// blocks [NHB,..): streaming — x->f16 cast, zero row, f16 weight pack.
__global__ __launch_bounds__(256) void k_bin(
    const int* __restrict__ ei, int* __restrict__ cnt,
    int* __restrict__ bsrc, unsigned short* __restrict__ bdstl,
    const float* __restrict__ x, __half* __restrict__ xh,
    const float* __restrict__ W1l, const float* __restrict__ W1r,
    __half2* __restrict__ wt1lh, __half2* __restrict__ wt1rh) {
    if (blockIdx.x < NHB) {
        __shared__ int h[NBUC];
        __shared__ int basep[NBUC];
        const int t = threadIdx.x;
        if (t < NBUC) h[t] = 0;
        __syncthreads();
        const int e0 = blockIdx.x * PB;
        const int e1 = min(e0 + PB, NE);
        for (int e = e0 + t; e < e1; e += 256)
            atomicAdd(&h[ei[NE + e] >> 10], 1);
        __syncthreads();
        if (t < NBUC) {
            const int c = h[t];
            basep[t] = c ? atomicAdd(&cnt[t], c) : 0;
            h[t] = 0;   // reuse as local cursor
        }
        __syncthreads();
        for (int e = e0 + t; e < e1; e += 256) {
            const int d = ei[NE + e];
            const int s = ei[e];
            const int k = d >> 10;
            const int r = atomicAdd(&h[k], 1);
            const int pos = k * BCAP + basep[k] + r;
            bsrc[pos] = s << 7;
            bdstl[pos] = (unsigned short)(d & 1023);
        }
        return;
    }
    const int tid = (blockIdx.x - NHB) * 256 + threadIdx.x;
    if (tid < NCC) {
        const float4 a = *((const float4*)x + (size_t)tid * 2);
        const float4 b = *((const float4*)x + (size_t)tid * 2 + 1);
        H8 o;
        o.h[0] = __floats2half2_rn(a.x, a.y);
        o.h[1] = __floats2half2_rn(a.z, a.w);
        o.h[2] = __floats2half2_rn(b.x, b.y);
        o.h[3] = __floats2half2_rn(b.z, b.w);
        *((H8*)xh + tid) = o;
    } else if (tid < NCC + 8) {
        H8 z;
        z.h[0] = z.h[1] = z.h[2] = z.h[3] = __float2half2_rn(0.f);
        *((H8*)(xh + (size_t)NN * FD) + (tid - NCC)) = z;
    } else if (tid < NSTR) {
        const int i = tid - (NCC + 8);   // j2*64 + k
        const int j2 = i >> 6, k = i & 63;
        wt1lh[i] = __floats2half2_rn(W1l[k * FD + 2 * j2], W1l[k * FD + 2 * j2 + 1]);
        wt1rh[i] = __floats2half2_rn(W1r[k * FD + 2 * j2], W1r[k * FD + 2 * j2 + 1]);
    }
}

// ---------------------------------------------------------------------------
// K2 k_D: one block per bucket (1024 threads): LDS degree count -> LDS scan
//   -> rowstart/deg (coalesced) -> LDS-cursor rank -> csr scatter (bucket
//   region L2-local). No global atomics.
__global__ __launch_bounds__(1024) void k_D(const int* __restrict__ bsrc,
                                            const unsigned short* __restrict__ bdstl,
                                            const int* __restrict__ cnt,
                                            int* __restrict__ rowstart,
                                            int* __restrict__ deg,
                                            int* __restrict__ csr) {
    __shared__ int dcnt[1024];
    __shared__ int sc[1024];
    __shared__ int cur[1024];
    const int t = threadIdx.x;
    const int k = blockIdx.x;
    const int nbase = k << 10;
    const int eb0 = k * BCAP;
    const int fill = cnt[k];
    dcnt[t] = 0;
    __syncthreads();
    for (int e = t; e < fill; e += 1024)
        atomicAdd(&dcnt[bdstl[eb0 + e]], 1);
    __syncthreads();
    const int v = dcnt[t];
    sc[t] = v;
    __syncthreads();
    for (int off = 1; off < 1024; off <<= 1) {
        const int add = (t >= off) ? sc[t - off] : 0;
        __syncthreads();
        sc[t] += add;
        __syncthreads();
    }
    const int rsl = eb0 + sc[t] - v;   // csr rowstart for node nbase+t
    cur[t] = rsl;
    if (nbase + t < NN) {
        rowstart[nbase + t] = rsl;
        deg[nbase + t] = v;
    }
    __syncthreads();
    for (int e = t; e < fill; e += 1024) {
        const int dl = bdstl[eb0 + e];
        const int pos = atomicAdd(&cur[dl], 1);
        csr[pos] = bsrc[eb0 + e];   // already src<<7
    }
}

// ---------------------------------------------------------------------------
// K3 k_l1: R16's proven core (tile blocks) + edge_out streaming blocks
//   appended (blockIdx >= NTILE): the 16MB conversion hides under the
//   latency-bound gather (k_l1 runs at 1.8TB/s, VALU 25% -> idle slots).
__global__ __launch_bounds__(512, 8) void k_l1(
    const int* __restrict__ csr, const int* __restrict__ rowstart,
    const int* __restrict__ deg, const __half* __restrict__ xh,
    const __half2* __restrict__ wt1lh, const float* __restrict__ b1,
    const __half2* __restrict__ wt1rh,
    const float* __restrict__ W2l, const float* __restrict__ b2,
    const float* __restrict__ W2r,
    float* __restrict__ pq,
    const int* __restrict__ ei, float* __restrict__ edge_out) {
    if (blockIdx.x >= NTILE) {
        const int i = (blockIdx.x - NTILE) * 512 + threadIdx.x;
        if (i < NB4) {
            const int4 v = *((const int4*)ei + i);
            float4 f;
            f.x = (float)v.x; f.y = (float)v.y; f.z = (float)v.z; f.w = (float)v.w;
            *((float4*)edge_out + i) = f;
        }
        return;
    }
    __shared__ __half2 sH[FD / 2][CHK + 1];
    __shared__ __half2 xH[FD / 2][CHK + 1];
    __shared__ float pacc[4 * CHK];
    const int lane = threadIdx.x & 63;
    const int wid = threadIdx.x >> 6;
    const int g = lane >> 3;
    const int sl = lane & 7;
    const int gb = g << 3;
    const int base = blockIdx.x * CHK;
    const char* xb = (const char*)xh;
    const unsigned slb = (unsigned)(sl << 4);
    const int ZOFF = NN << 7;

    if (threadIdx.x < 4 * CHK) pacc[threadIdx.x] = 0.f;

    const int nl = wid * 8 + g;
    const int n = base + nl;
    const bool ok = n < NN;
    const int nn = ok ? n : NN - 1;
    const int d = deg[nn];
    const int rs = rowstart[nn];

    int dmax = d;
    dmax = max(dmax, __shfl_xor(dmax, 8));
    dmax = max(dmax, __shfl_xor(dmax, 16));
    dmax = max(dmax, __shfl_xor(dmax, 32));
    const int nch = __builtin_amdgcn_readfirstlane((dmax + 7) >> 3);

    H8 acc;
    acc.h[0] = acc.h[1] = acc.h[2] = acc.h[3] = __float2half2_rn(0.f);

    for (int c = 0; c < nch; ++c) {
        const int jb = c << 3;
        const int ia = min(rs + jb + sl, NBUC * BCAP - 1);
        const int raw = csr[ia];
        const int offs = (jb + sl < d) ? raw : ZOFF;
        H8 buf[8];
#pragma unroll
        for (int t = 0; t < 8; ++t) {
            const unsigned ob = (unsigned)__shfl(offs, gb + t);
            buf[t] = *(const H8*)(xb + (size_t)(ob + slb));
        }
        __builtin_amdgcn_sched_barrier(0);
#pragma unroll
        for (int t = 0; t < 8; ++t) {
            acc.h[0] = __hadd2(acc.h[0], buf[t].h[0]);
            acc.h[1] = __hadd2(acc.h[1], buf[t].h[1]);
            acc.h[2] = __hadd2(acc.h[2], buf[t].h[2]);
            acc.h[3] = __hadd2(acc.h[3], buf[t].h[3]);
        }
    }

    if (ok) {
        const __half2 hinv = __float2half2_rn(1.0f / (float)max(d, 1));
        const H8 xv = *(const H8*)(xb + (size_t)(((unsigned)nn << 7) + slb));
#pragma unroll
        for (int t = 0; t < 4; ++t) {
            sH[sl * 4 + t][nl] = __hmul2(acc.h[t], hinv);
            xH[sl * 4 + t][nl] = xv.h[t];
        }
    }
    __syncthreads();

    const int kbase = __builtin_amdgcn_readfirstlane(wid * 8);
    float h[8];
#pragma unroll
    for (int t = 0; t < 8; ++t) h[t] = b1[kbase + t];
#pragma unroll 4
    for (int j2 = 0; j2 < FD / 2; ++j2) {
        const __half2 sj = sH[j2][lane];
        const __half2 xj = xH[j2][lane];
        const __half2* wl = wt1lh + j2 * FD + kbase;
        const __half2* wr = wt1rh + j2 * FD + kbase;
#pragma unroll
        for (int t = 0; t < 8; ++t) {
            h[t] = fdot2f(sj, wl[t], h[t]);
            h[t] = fdot2f(xj, wr[t], h[t]);
        }
    }

    float p0 = 0.f, p1 = 0.f, q0 = 0.f, q1 = 0.f;
#pragma unroll
    for (int t = 0; t < 8; ++t) {
        const float r = fmaxf(h[t], 0.f);
        p0 += r * W2l[kbase + t];
        p1 += r * W2l[FD + kbase + t];
        q0 += r * W2r[kbase + t];
        q1 += r * W2r[FD + kbase + t];
    }
    atomicAdd(&pacc[0 * CHK + lane], p0);
    atomicAdd(&pacc[1 * CHK + lane], p1);
    atomicAdd(&pacc[2 * CHK + lane], q0);
    atomicAdd(&pacc[3 * CHK + lane], q1);
    __syncthreads();

    {
        const int t = threadIdx.x;
        if (t < 4 * CHK) {
            const int nw = base + (t >> 2);
            if (nw < NN) {
                const int c = t & 3;
                float vv = pacc[c * CHK + (t >> 2)];
                if (c == 2) vv += b2[0];
                if (c == 3) vv += b2[1];
                pq[(size_t)nw * 4 + c] = vv;
            }
        }
    }
}

// ---------------------------------------------------------------------------
// K4 k_l2: layer-2 mean aggregation of p + final add (proven version).
__global__ void k_l2(const int* __restrict__ csr, const int* __restrict__ rowstart,
                     const int* __restrict__ deg, const float* __restrict__ pq,
                     float* __restrict__ out) {
    const int gw = (blockIdx.x * blockDim.x + threadIdx.x) >> 6;
    const int lane = threadIdx.x & 63;
    const int sub = lane >> 4;
    const int sl = lane & 15;
    const int n = gw * 4 + sub;
    if (n >= NN) return;
    const int rs = rowstart[n];
    const int d = deg[n];
    const char* pb = (const char*)pq;
    float a0 = 0.f, a1 = 0.f;
    for (int i = sl; i < d; i += 16) {
        const unsigned v = (unsigned)csr[rs + i];
        const float2 p = *(const float2*)(pb + (size_t)(v >> 3));
        a0 += p.x;
        a1 += p.y;
    }
#pragma unroll
    for (int off = 8; off; off >>= 1) {
        a0 += __shfl_xor(a0, off);
        a1 += __shfl_xor(a1, off);
    }
    if (sl == 0) {
        const float inv = 1.0f / (float)max(d, 1);
        const float2 q = *(const float2*)(pq + 4 * (size_t)n + 2);
        *(float2*)(out + 2 * (size_t)n) = make_float2(a0 * inv + q.x, a1 * inv + q.y);
    }
}

// ---------------------------------------------------------------------------
extern "C" void kernel_launch(void* const* d_in, const int* in_sizes, int n_in,
                              void* d_out, int out_size, void* d_ws, size_t ws_size,
                              hipStream_t stream) {
    const float* x   = (const float*)d_in[0];
    const int*   ei  = (const int*)d_in[1];
    const float* W1l = (const float*)d_in[2];
    const float* b1  = (const float*)d_in[3];
    const float* W1r = (const float*)d_in[4];
    const float* W2l = (const float*)d_in[5];
    const float* b2  = (const float*)d_in[6];
    const float* W2r = (const float*)d_in[7];

    float* out      = (float*)d_out;   // N*2 floats
    float* edge_out = out + 2 * NN;    // 2*E floats

    int*    wsi      = (int*)d_ws;
    int*    cnt      = wsi + OFF_CNT;
    int*    bsrc     = wsi + OFF_BSRC;
    unsigned short* bdstl = (unsigned short*)(wsi + OFF_BDST);
    int*    rowstart = wsi + OFF_ROW;
    int*    deg      = wsi + OFF_DEG;
    int*    csr      = wsi + OFF_CSR;
    float*  pq       = (float*)d_ws + OFF_PQ;
    __half2* wt1lh   = (__half2*)((float*)d_ws + OFF_WTH);
    __half2* wt1rh   = wt1lh + 2048;
    __half*  xh      = (__half*)((float*)d_ws + OFF_XH);

    hipMemsetAsync(cnt, 0, 128 * sizeof(int), stream);

    const int nstrb = (NSTR + 255) / 256;
    k_bin<<<NHB + nstrb, 256, 0, stream>>>(ei, cnt, bsrc, bdstl, x, xh,
                                           W1l, W1r, wt1lh, wt1rh);
    k_D<<<NBUC, 1024, 0, stream>>>(bsrc, bdstl, cnt, rowstart, deg, csr);
    k_l1<<<NTILE + NEOB, 512, 0, stream>>>(csr, rowstart, deg, xh,
                                           wt1lh, b1, wt1rh,
                                           W2l, b2, W2r, pq, ei, edge_out);
    k_l2<<<((NN + 3) / 4 * 64 + 255) / 256, 256, 0, stream>>>(
        csr, rowstart, deg, pq, out);
}

// Round 18
// 107.686 us; speedup vs baseline: 1.4274x; 1.0081x over previous
//
#include <hip/hip_runtime.h>
#include <hip/hip_fp16.h>

#define NN 100000    // nodes
#define NE 1000000   // edges
#define FD 64        // feature dim
#define CHK 64       // nodes per block tile in k_l1
#define NBUC 98      // buckets of 1024 nodes (dst >> 10)
#define NHB 256      // binning blocks
#define PB 3907      // edges per binning block (ceil)
#define BCAP 12288   // bucket capacity (max fill ~10.5k, 20-sigma margin)

typedef _Float16 f16x2 __attribute__((ext_vector_type(2)));

#if defined(__has_builtin)
#if __has_builtin(__builtin_amdgcn_fdot2)
#define HAVE_FDOT2 1
#endif
#endif

__device__ __forceinline__ float fdot2f(__half2 a, __half2 b, float c) {
#ifdef HAVE_FDOT2
    return __builtin_amdgcn_fdot2(__builtin_bit_cast(f16x2, a),
                                  __builtin_bit_cast(f16x2, b), c, false);
#else
    const float2 af = __half22float2(a), bf = __half22float2(b);
    return c + af.x * bf.x + af.y * bf.y;
#endif
}

// ws layout (4-byte units), total ~27.2 MB (<= 28.4 proven):
#define OFF_CNT  0                          // 98 bucket cursors (+pad to 128)
#define OFF_BSRC 128                        // NBUC*BCAP binned src<<7
#define OFF_BDST (OFF_BSRC + NBUC * BCAP)   // NBUC*BCAP/2 local dst (ushort)
#define OFF_ROW  (OFF_BDST + NBUC * BCAP / 2)  // NN rowstart
#define OFF_DEG  (OFF_ROW + NN)             // NN degree
#define OFF_CSR  (OFF_DEG + NN)             // NBUC*BCAP src<<7, dst-grouped
#define OFF_PQ   (OFF_CSR + NBUC * BCAP)    // 4NN
#define OFF_WTH  (OFF_PQ + 4 * NN)          // 2*2048 half2
#define OFF_XH   (OFF_WTH + 4096)           // (NN+1)*64 halves

struct alignas(16) H8 { __half2 h[4]; };

#define NCC (NN * FD / 8)   // 800000 cast threads
#define NSTR (NCC + 8 + 2048)
#define NSTRB ((NSTR + 1023) / 1024)        // 784 streaming blocks in k_D
#define NB4 (2 * NE / 4)    // 500000 edge_out int4 threads
#define NTILE ((NN + CHK - 1) / CHK)        // 1563 k_l1 tile blocks
#define NEOB ((NB4 + 511) / 512)            // 977 edge_out blocks in k_l1

// ---------------------------------------------------------------------------
// K1 k_bin: pure 2-pass bin of edges by dst bucket (streams moved to k_D).
//   pass1: LDS count per bucket; ONE global atomicAdd per (block,bucket).
//   pass2: re-read chunk (L2-hot), LDS-cursor scatter -> bsrc/bdstl.
__global__ __launch_bounds__(256) void k_bin(
    const int* __restrict__ ei, int* __restrict__ cnt,
    int* __restrict__ bsrc, unsigned short* __restrict__ bdstl) {
    __shared__ int h[NBUC];
    __shared__ int basep[NBUC];
    const int t = threadIdx.x;
    if (t < NBUC) h[t] = 0;
    __syncthreads();
    const int e0 = blockIdx.x * PB;
    const int e1 = min(e0 + PB, NE);
    for (int e = e0 + t; e < e1; e += 256)
        atomicAdd(&h[ei[NE + e] >> 10], 1);
    __syncthreads();
    if (t < NBUC) {
        const int c = h[t];
        basep[t] = c ? atomicAdd(&cnt[t], c) : 0;
        h[t] = 0;   // reuse as local cursor
    }
    __syncthreads();
    for (int e = e0 + t; e < e1; e += 256) {
        const int d = ei[NE + e];
        const int s = ei[e];
        const int k = d >> 10;
        const int r = atomicAdd(&h[k], 1);
        const int pos = k * BCAP + basep[k] + r;
        bsrc[pos] = s << 7;
        bdstl[pos] = (unsigned short)(d & 1023);
    }
}

// ---------------------------------------------------------------------------
// K2 k_D: blocks [0,NBUC): per-bucket LDS degree count -> wave-shfl scan
//   (2 barriers vs 20) -> rowstart/deg -> LDS-cursor rank -> csr scatter.
// blocks [NBUC,..): streaming — x->f16 cast, zero row, f16 weight pack
//   (hidden under the barrier-heavy bucket blocks; R17 lesson applied).
__global__ __launch_bounds__(1024) void k_D(
    const int* __restrict__ bsrc, const unsigned short* __restrict__ bdstl,
    const int* __restrict__ cnt, int* __restrict__ rowstart,
    int* __restrict__ deg, int* __restrict__ csr,
    const float* __restrict__ x, __half* __restrict__ xh,
    const float* __restrict__ W1l, const float* __restrict__ W1r,
    __half2* __restrict__ wt1lh, __half2* __restrict__ wt1rh) {
    if (blockIdx.x >= NBUC) {
        const int tid = (blockIdx.x - NBUC) * 1024 + threadIdx.x;
        if (tid < NCC) {
            const float4 a = *((const float4*)x + (size_t)tid * 2);
            const float4 b = *((const float4*)x + (size_t)tid * 2 + 1);
            H8 o;
            o.h[0] = __floats2half2_rn(a.x, a.y);
            o.h[1] = __floats2half2_rn(a.z, a.w);
            o.h[2] = __floats2half2_rn(b.x, b.y);
            o.h[3] = __floats2half2_rn(b.z, b.w);
            *((H8*)xh + tid) = o;
        } else if (tid < NCC + 8) {
            H8 z;
            z.h[0] = z.h[1] = z.h[2] = z.h[3] = __float2half2_rn(0.f);
            *((H8*)(xh + (size_t)NN * FD) + (tid - NCC)) = z;
        } else if (tid < NSTR) {
            const int i = tid - (NCC + 8);   // j2*64 + k
            const int j2 = i >> 6, k = i & 63;
            wt1lh[i] = __floats2half2_rn(W1l[k * FD + 2 * j2],
                                         W1l[k * FD + 2 * j2 + 1]);
            wt1rh[i] = __floats2half2_rn(W1r[k * FD + 2 * j2],
                                         W1r[k * FD + 2 * j2 + 1]);
        }
        return;
    }
    __shared__ int dcnt[1024];
    __shared__ int cur[1024];
    __shared__ int wsum[16];
    const int t = threadIdx.x;
    const int lane = t & 63;
    const int wv = t >> 6;   // 0..15
    const int k = blockIdx.x;
    const int nbase = k << 10;
    const int eb0 = k * BCAP;
    const int fill = cnt[k];
    dcnt[t] = 0;
    __syncthreads();
    for (int e = t; e < fill; e += 1024)
        atomicAdd(&dcnt[bdstl[eb0 + e]], 1);
    __syncthreads();
    const int v = dcnt[t];
    // in-wave inclusive scan (no barriers)
    int inc = v;
#pragma unroll
    for (int off = 1; off < 64; off <<= 1) {
        const int u = __shfl_up(inc, off);
        if (lane >= off) inc += u;
    }
    if (lane == 63) wsum[wv] = inc;
    __syncthreads();
    if (t < 16) {   // cross-wave scan (16 values, wave 0, lockstep)
        int s = wsum[t];
#pragma unroll
        for (int off = 1; off < 16; off <<= 1) {
            const int u = __shfl_up(s, off);
            if (t >= off) s += u;
        }
        wsum[t] = s;   // inclusive wave totals
    }
    __syncthreads();
    const int woff = wv ? wsum[wv - 1] : 0;
    const int rsl = eb0 + woff + inc - v;   // csr rowstart for node nbase+t
    cur[t] = rsl;
    if (nbase + t < NN) {
        rowstart[nbase + t] = rsl;
        deg[nbase + t] = v;
    }
    __syncthreads();
    for (int e = t; e < fill; e += 1024) {
        const int dl = bdstl[eb0 + e];
        const int pos = atomicAdd(&cur[dl], 1);
        csr[pos] = bsrc[eb0 + e];   // already src<<7
    }
}

// ---------------------------------------------------------------------------
// K3 k_l1: R17's proven core (tile blocks) + edge_out streaming blocks.
__global__ __launch_bounds__(512, 8) void k_l1(
    const int* __restrict__ csr, const int* __restrict__ rowstart,
    const int* __restrict__ deg, const __half* __restrict__ xh,
    const __half2* __restrict__ wt1lh, const float* __restrict__ b1,
    const __half2* __restrict__ wt1rh,
    const float* __restrict__ W2l, const float* __restrict__ b2,
    const float* __restrict__ W2r,
    float* __restrict__ pq,
    const int* __restrict__ ei, float* __restrict__ edge_out) {
    if (blockIdx.x >= NTILE) {
        const int i = (blockIdx.x - NTILE) * 512 + threadIdx.x;
        if (i < NB4) {
            const int4 v = *((const int4*)ei + i);
            float4 f;
            f.x = (float)v.x; f.y = (float)v.y; f.z = (float)v.z; f.w = (float)v.w;
            *((float4*)edge_out + i) = f;
        }
        return;
    }
    __shared__ __half2 sH[FD / 2][CHK + 1];
    __shared__ __half2 xH[FD / 2][CHK + 1];
    __shared__ float pacc[4 * CHK];
    const int lane = threadIdx.x & 63;
    const int wid = threadIdx.x >> 6;
    const int g = lane >> 3;
    const int sl = lane & 7;
    const int gb = g << 3;
    const int base = blockIdx.x * CHK;
    const char* xb = (const char*)xh;
    const unsigned slb = (unsigned)(sl << 4);
    const int ZOFF = NN << 7;

    if (threadIdx.x < 4 * CHK) pacc[threadIdx.x] = 0.f;

    const int nl = wid * 8 + g;
    const int n = base + nl;
    const bool ok = n < NN;
    const int nn = ok ? n : NN - 1;
    const int d = deg[nn];
    const int rs = rowstart[nn];

    int dmax = d;
    dmax = max(dmax, __shfl_xor(dmax, 8));
    dmax = max(dmax, __shfl_xor(dmax, 16));
    dmax = max(dmax, __shfl_xor(dmax, 32));
    const int nch = __builtin_amdgcn_readfirstlane((dmax + 7) >> 3);

    H8 acc;
    acc.h[0] = acc.h[1] = acc.h[2] = acc.h[3] = __float2half2_rn(0.f);

    for (int c = 0; c < nch; ++c) {
        const int jb = c << 3;
        const int ia = min(rs + jb + sl, NBUC * BCAP - 1);
        const int raw = csr[ia];
        const int offs = (jb + sl < d) ? raw : ZOFF;
        H8 buf[8];
#pragma unroll
        for (int t = 0; t < 8; ++t) {
            const unsigned ob = (unsigned)__shfl(offs, gb + t);
            buf[t] = *(const H8*)(xb + (size_t)(ob + slb));
        }
        __builtin_amdgcn_sched_barrier(0);
#pragma unroll
        for (int t = 0; t < 8; ++t) {
            acc.h[0] = __hadd2(acc.h[0], buf[t].h[0]);
            acc.h[1] = __hadd2(acc.h[1], buf[t].h[1]);
            acc.h[2] = __hadd2(acc.h[2], buf[t].h[2]);
            acc.h[3] = __hadd2(acc.h[3], buf[t].h[3]);
        }
    }

    if (ok) {
        const __half2 hinv = __float2half2_rn(1.0f / (float)max(d, 1));
        const H8 xv = *(const H8*)(xb + (size_t)(((unsigned)nn << 7) + slb));
#pragma unroll
        for (int t = 0; t < 4; ++t) {
            sH[sl * 4 + t][nl] = __hmul2(acc.h[t], hinv);
            xH[sl * 4 + t][nl] = xv.h[t];
        }
    }
    __syncthreads();

    const int kbase = __builtin_amdgcn_readfirstlane(wid * 8);
    float h[8];
#pragma unroll
    for (int t = 0; t < 8; ++t) h[t] = b1[kbase + t];
#pragma unroll 4
    for (int j2 = 0; j2 < FD / 2; ++j2) {
        const __half2 sj = sH[j2][lane];
        const __half2 xj = xH[j2][lane];
        const __half2* wl = wt1lh + j2 * FD + kbase;
        const __half2* wr = wt1rh + j2 * FD + kbase;
#pragma unroll
        for (int t = 0; t < 8; ++t) {
            h[t] = fdot2f(sj, wl[t], h[t]);
            h[t] = fdot2f(xj, wr[t], h[t]);
        }
    }

    float p0 = 0.f, p1 = 0.f, q0 = 0.f, q1 = 0.f;
#pragma unroll
    for (int t = 0; t < 8; ++t) {
        const float r = fmaxf(h[t], 0.f);
        p0 += r * W2l[kbase + t];
        p1 += r * W2l[FD + kbase + t];
        q0 += r * W2r[kbase + t];
        q1 += r * W2r[FD + kbase + t];
    }
    atomicAdd(&pacc[0 * CHK + lane], p0);
    atomicAdd(&pacc[1 * CHK + lane], p1);
    atomicAdd(&pacc[2 * CHK + lane], q0);
    atomicAdd(&pacc[3 * CHK + lane], q1);
    __syncthreads();

    {
        const int t = threadIdx.x;
        if (t < 4 * CHK) {
            const int nw = base + (t >> 2);
            if (nw < NN) {
                const int c = t & 3;
                float vv = pacc[c * CHK + (t >> 2)];
                if (c == 2) vv += b2[0];
                if (c == 3) vv += b2[1];
                pq[(size_t)nw * 4 + c] = vv;
            }
        }
    }
}

// ---------------------------------------------------------------------------
// K4 k_l2: layer-2 mean aggregation of p + final add (proven version).
__global__ void k_l2(const int* __restrict__ csr, const int* __restrict__ rowstart,
                     const int* __restrict__ deg, const float* __restrict__ pq,
                     float* __restrict__ out) {
    const int gw = (blockIdx.x * blockDim.x + threadIdx.x) >> 6;
    const int lane = threadIdx.x & 63;
    const int sub = lane >> 4;
    const int sl = lane & 15;
    const int n = gw * 4 + sub;
    if (n >= NN) return;
    const int rs = rowstart[n];
    const int d = deg[n];
    const char* pb = (const char*)pq;
    float a0 = 0.f, a1 = 0.f;
    for (int i = sl; i < d; i += 16) {
        const unsigned v = (unsigned)csr[rs + i];
        const float2 p = *(const float2*)(pb + (size_t)(v >> 3));
        a0 += p.x;
        a1 += p.y;
    }
#pragma unroll
    for (int off = 8; off; off >>= 1) {
        a0 += __shfl_xor(a0, off);
        a1 += __shfl_xor(a1, off);
    }
    if (sl == 0) {
        const float inv = 1.0f / (float)max(d, 1);
        const float2 q = *(const float2*)(pq + 4 * (size_t)n + 2);
        *(float2*)(out + 2 * (size_t)n) = make_float2(a0 * inv + q.x, a1 * inv + q.y);
    }
}

// ---------------------------------------------------------------------------
extern "C" void kernel_launch(void* const* d_in, const int* in_sizes, int n_in,
                              void* d_out, int out_size, void* d_ws, size_t ws_size,
                              hipStream_t stream) {
    const float* x   = (const float*)d_in[0];
    const int*   ei  = (const int*)d_in[1];
    const float* W1l = (const float*)d_in[2];
    const float* b1  = (const float*)d_in[3];
    const float* W1r = (const float*)d_in[4];
    const float* W2l = (const float*)d_in[5];
    const float* b2  = (const float*)d_in[6];
    const float* W2r = (const float*)d_in[7];

    float* out      = (float*)d_out;   // N*2 floats
    float* edge_out = out + 2 * NN;    // 2*E floats

    int*    wsi      = (int*)d_ws;
    int*    cnt      = wsi + OFF_CNT;
    int*    bsrc     = wsi + OFF_BSRC;
    unsigned short* bdstl = (unsigned short*)(wsi + OFF_BDST);
    int*    rowstart = wsi + OFF_ROW;
    int*    deg      = wsi + OFF_DEG;
    int*    csr      = wsi + OFF_CSR;
    float*  pq       = (float*)d_ws + OFF_PQ;
    __half2* wt1lh   = (__half2*)((float*)d_ws + OFF_WTH);
    __half2* wt1rh   = wt1lh + 2048;
    __half*  xh      = (__half*)((float*)d_ws + OFF_XH);

    hipMemsetAsync(cnt, 0, 128 * sizeof(int), stream);

    k_bin<<<NHB, 256, 0, stream>>>(ei, cnt, bsrc, bdstl);
    k_D<<<NBUC + NSTRB, 1024, 0, stream>>>(bsrc, bdstl, cnt, rowstart, deg, csr,
                                           x, xh, W1l, W1r, wt1lh, wt1rh);
    k_l1<<<NTILE + NEOB, 512, 0, stream>>>(csr, rowstart, deg, xh,
                                           wt1lh, b1, wt1rh,
                                           W2l, b2, W2r, pq, ei, edge_out);
    k_l2<<<((NN + 3) / 4 * 64 + 255) / 256, 256, 0, stream>>>(
        csr, rowstart, deg, pq, out);
}